// Round 21
// baseline (129.756 us; speedup 1.0000x reference)
//
#include <hip/hip_runtime.h>
#include <math.h>

#define CT    320
#define NPTS  1024
#define DFEAT 256
#define DPOS  64
#define KSEL  32
#define QSTEP 6.103515625e-05f          // 2^-14, thr(m) = m*QSTEP - 1 (exact)

typedef __attribute__((ext_vector_type(8))) short short8;   // 8 bf16 (4 VGPRs)
typedef __attribute__((ext_vector_type(4))) float f32x4;

__device__ __forceinline__ unsigned bf16_rne(float x) {
  const unsigned u = __float_as_uint(x);
  return (u + 0x7FFFu + ((u >> 16) & 1u)) >> 16;
}
__device__ __forceinline__ float bf16_back(unsigned h) {
  return __uint_as_float(h << 16);
}

// ========== Kernel C2: normalized pos -> transposed bf16x3 planes ==========
// 64 blocks x 256 threads; thread owns point j: coalesced column read,
// rnj, split phat into (hi, mid, lo) bf16, write phatT[j][d] rows (128B).
__global__ __launch_bounds__(256) void gnn_phat(const float* __restrict__ in,
                                                unsigned short* __restrict__ ph0,
                                                unsigned short* __restrict__ ph1,
                                                unsigned short* __restrict__ ph2) {
  const int b     = blockIdx.x;
  const int batch = b >> 2;
  const int j     = ((b & 3) << 8) + threadIdx.x;
  const float* __restrict__ pbase = in + (size_t)batch * CT * NPTS + (size_t)DFEAT * NPTS;

  float x[DPOS];
  float ssq = 0.f;
#pragma unroll
  for (int d = 0; d < DPOS; ++d) {
    x[d] = pbase[(size_t)d * NPTS + j];
    ssq = fmaf(x[d], x[d], ssq);
  }
  const float rn = 1.0f / fmaxf(sqrtf(ssq), 1e-12f);

  const size_t rowoff = ((size_t)batch * NPTS + j) * DPOS;   // elements
  uint4* r0 = (uint4*)(ph0 + rowoff);
  uint4* r1 = (uint4*)(ph1 + rowoff);
  uint4* r2 = (uint4*)(ph2 + rowoff);
#pragma unroll
  for (int qd = 0; qd < 8; ++qd) {
    unsigned a0[8], a1[8], a2[8];
#pragma unroll
    for (int e = 0; e < 8; ++e) {
      const float y = x[qd * 8 + e] * rn;
      a0[e] = bf16_rne(y);
      const float s1 = y - bf16_back(a0[e]);
      a1[e] = bf16_rne(s1);
      const float s2 = s1 - bf16_back(a1[e]);
      a2[e] = bf16_rne(s2);
    }
    uint4 v;
    v.x = a0[0] | (a0[1] << 16); v.y = a0[2] | (a0[3] << 16);
    v.z = a0[4] | (a0[5] << 16); v.w = a0[6] | (a0[7] << 16);
    r0[qd] = v;
    v.x = a1[0] | (a1[1] << 16); v.y = a1[2] | (a1[3] << 16);
    v.z = a1[4] | (a1[5] << 16); v.w = a1[6] | (a1[7] << 16);
    r1[qd] = v;
    v.x = a2[0] | (a2[1] << 16); v.y = a2[2] | (a2[3] << 16);
    v.z = a2[4] | (a2[5] << 16); v.w = a2[6] | (a2[7] << 16);
    r2[qd] = v;
  }
}

// ====== Kernel A: MFMA bf16x3 sim + per-lane topk + merge + softmax ========
// 1024 blocks x 256 threads; 16 rows/block; wave w owns j-strip w*256..+255.
// MFMA 16x16x32: A = j-tiles (m), B = query rows (n) -> lane l holds 64 sim
// values of query row l&15 at j = w*256 + nt*16 + (l>>4)*4 + r. 6 term-pairs
// of the bf16x3 split (err ~5e-7, fp32-class). Per-lane threshold search
// (all 16 rows in parallel, zero ballots), strip-partial top-32 -> proven
// 128->32 merge + softmax.
__global__ __launch_bounds__(256, 2) void gnn_sim_topk(const unsigned short* __restrict__ ph0,
                                                       const unsigned short* __restrict__ ph1,
                                                       const unsigned short* __restrict__ ph2,
                                                       float2* __restrict__ pairs) {
  __shared__ float cand[16][260];      // 16 rows x 128 interleaved (v,j) pairs

  const int p     = blockIdx.x;
  const int batch = ((p & 7) << 1) | ((p >> 3) & 1);   // 2 batches per XCD
  const int chunk = p >> 4;            // 0..63
  const int i0    = chunk * 16;
  const int tid   = threadIdx.x;
  const int w     = tid >> 6;
  const int lane  = tid & 63;
  const int il    = lane & 15;
  const int g     = lane >> 4;

  const size_t bb = (size_t)batch * NPTS;

  // B-frags: query rows i0+il, k-slice ks*32 + g*8 .. +7 (3 planes)
  short8 bfr[2][3];
  {
    const size_t off = (bb + i0 + il) * DPOS + g * 8;
#pragma unroll
    for (int ks = 0; ks < 2; ++ks) {
      bfr[ks][0] = *(const short8*)(ph0 + off + ks * 32);
      bfr[ks][1] = *(const short8*)(ph1 + off + ks * 32);
      bfr[ks][2] = *(const short8*)(ph2 + off + ks * 32);
    }
  }

  f32x4 acc[16];
#pragma unroll
  for (int nt = 0; nt < 16; ++nt) acc[nt] = (f32x4){0.f, 0.f, 0.f, 0.f};

  const size_t jo = (bb + w * 256 + il) * DPOS + g * 8;

#pragma unroll
  for (int ks = 0; ks < 2; ++ks) {
    short8 afr[16];
    // A-plane 0: pairs with B-planes 0,1,2
#pragma unroll
    for (int nt = 0; nt < 16; ++nt)
      afr[nt] = *(const short8*)(ph0 + jo + (size_t)nt * 16 * DPOS + ks * 32);
#pragma unroll
    for (int nt = 0; nt < 16; ++nt)
      acc[nt] = __builtin_amdgcn_mfma_f32_16x16x32_bf16(afr[nt], bfr[ks][0], acc[nt], 0, 0, 0);
#pragma unroll
    for (int nt = 0; nt < 16; ++nt)
      acc[nt] = __builtin_amdgcn_mfma_f32_16x16x32_bf16(afr[nt], bfr[ks][1], acc[nt], 0, 0, 0);
#pragma unroll
    for (int nt = 0; nt < 16; ++nt)
      acc[nt] = __builtin_amdgcn_mfma_f32_16x16x32_bf16(afr[nt], bfr[ks][2], acc[nt], 0, 0, 0);
    // A-plane 1: pairs with B-planes 0,1
#pragma unroll
    for (int nt = 0; nt < 16; ++nt)
      afr[nt] = *(const short8*)(ph1 + jo + (size_t)nt * 16 * DPOS + ks * 32);
#pragma unroll
    for (int nt = 0; nt < 16; ++nt)
      acc[nt] = __builtin_amdgcn_mfma_f32_16x16x32_bf16(afr[nt], bfr[ks][0], acc[nt], 0, 0, 0);
#pragma unroll
    for (int nt = 0; nt < 16; ++nt)
      acc[nt] = __builtin_amdgcn_mfma_f32_16x16x32_bf16(afr[nt], bfr[ks][1], acc[nt], 0, 0, 0);
    // A-plane 2: pairs with B-plane 0
#pragma unroll
    for (int nt = 0; nt < 16; ++nt)
      afr[nt] = *(const short8*)(ph2 + jo + (size_t)nt * 16 * DPOS + ks * 32);
#pragma unroll
    for (int nt = 0; nt < 16; ++nt)
      acc[nt] = __builtin_amdgcn_mfma_f32_16x16x32_bf16(afr[nt], bfr[ks][0], acc[nt], 0, 0, 0);
  }

  // ---- per-lane strip top-32 (row = il; 64 values in acc; rows parallel) ----
  const int jb = w * 256 + g * 4;      // + nt*16 + r
  int lo = 0;
#pragma unroll
  for (int bit = 16384; bit >= 1; bit >>= 1) {
    const float thrf = (float)(lo + bit) * QSTEP - 1.0f;
    int cnt = 0;
#pragma unroll
    for (int nt = 0; nt < 16; ++nt)
#pragma unroll
      for (int r = 0; r < 4; ++r) cnt += (acc[nt][r] >= thrf) ? 1 : 0;
    const int c2 = cnt + __shfl_xor(cnt, 16);
    const int c4 = c2 + __shfl_xor(c2, 32);
    if (c4 >= KSEL) lo += bit;
  }
  const float thr_h = (float)(lo + 1) * QSTEP - 1.0f;
  const float thr_l = (float)lo * QSTEP - 1.0f;

  int lcnt = 0;
#pragma unroll
  for (int nt = 0; nt < 16; ++nt)
#pragma unroll
    for (int r = 0; r < 4; ++r) lcnt += (acc[nt][r] >= thr_h) ? 1 : 0;
  const int cO = __shfl_xor(lcnt, 16);       // count of group g^1
  const int cT = __shfl_xor(lcnt, 32);       // g^2
  const int cH = __shfl_xor(cO, 32);         // g^3
  const int cbase = lcnt + cO + cT + cH;
  const int pre = (g == 0) ? 0 : (g == 1) ? cO : (g == 2) ? (cT + cH) : (cO + cT + cH);

  // definite members -> cand[il][strip slots w*32 + ...]
  {
    int pos = pre;
#pragma unroll
    for (int nt = 0; nt < 16; ++nt) {
#pragma unroll
      for (int r = 0; r < 4; ++r) {
        if (acc[nt][r] >= thr_h) {
          *(float2*)&cand[il][2 * (w * KSEL + pos)] =
              make_float2(acc[nt][r], __int_as_float(jb + nt * 16 + r));
          ++pos;
        }
      }
    }
  }
  // boundary: exact (v desc, j asc); quad-uniform need -> shfl safe
  unsigned long long bm = 0ull;
#pragma unroll
  for (int nt = 0; nt < 16; ++nt)
#pragma unroll
    for (int r = 0; r < 4; ++r)
      if (acc[nt][r] >= thr_l && acc[nt][r] < thr_h) bm |= (1ull << (nt * 4 + r));
  const int need = KSEL - cbase;
  for (int it = 0; it < need; ++it) {
    float bv = -2.0f; int bj = 0x7fffffff; int bs = 0;
#pragma unroll
    for (int nt = 0; nt < 16; ++nt) {
#pragma unroll
      for (int r = 0; r < 4; ++r) {
        if (((bm >> (nt * 4 + r)) & 1ull) && acc[nt][r] > bv) {
          bv = acc[nt][r]; bj = jb + nt * 16 + r; bs = nt * 4 + r;
        }
      }
    }
    float rv = bv; int rj = bj;
    {
      const float ov = __shfl_xor(rv, 16); const int oj = __shfl_xor(rj, 16);
      if (ov > rv || (ov == rv && oj < rj)) { rv = ov; rj = oj; }
    }
    {
      const float ov = __shfl_xor(rv, 32); const int oj = __shfl_xor(rj, 32);
      if (ov > rv || (ov == rv && oj < rj)) { rv = ov; rj = oj; }
    }
    if (bv == rv && bj == rj) {              // unique owner (j unique)
      *(float2*)&cand[il][2 * (w * KSEL + cbase + it)] = make_float2(bv, __int_as_float(bj));
      bm &= ~(1ull << bs);
    }
  }
  __syncthreads();

  // ---- merge 128 -> exact top-32 + softmax; wave w owns rows w*4..w*4+3 ----
#pragma unroll
  for (int rr = 0; rr < 4; ++rr) {
    const int r = w * 4 + rr;
    const float4 c4 = *(const float4*)&cand[r][lane * 4];   // 2 pairs per lane
    float v2[2] = { c4.x, c4.z };
    int   j2[2] = { __float_as_int(c4.y), __float_as_int(c4.w) };
    int lo2 = 0;
#pragma unroll
    for (int bit = 16384; bit >= 1; bit >>= 1) {
      const float thrf = (float)(lo2 + bit) * QSTEP - 1.0f;
      const int cnt = (int)__popcll(__ballot(v2[0] >= thrf)) +
                      (int)__popcll(__ballot(v2[1] >= thrf));
      if (cnt >= KSEL) lo2 += bit;
    }
    const float th = (float)(lo2 + 1) * QSTEP - 1.0f;
    const float tl = (float)lo2 * QSTEP - 1.0f;
    int cb = 0; unsigned cm = 0u;
#pragma unroll
    for (int t = 0; t < 2; ++t) {
      const bool hi = (v2[t] >= th);
      const unsigned long long m = __ballot(hi);
      if (hi) {
        const int ps = cb + (int)__builtin_amdgcn_mbcnt_hi(
            (unsigned)(m >> 32), __builtin_amdgcn_mbcnt_lo((unsigned)m, 0u));
        *(float2*)&cand[r][2 * ps] = make_float2(v2[t], __int_as_float(j2[t]));
      }
      cb += (int)__popcll(m);
      if (v2[t] >= tl && !hi) cm |= (1u << t);
    }
    const int nd = KSEL - cb;
    for (int it = 0; it < nd; ++it) {
      float bv = -2.0f; int bj = 0x7fffffff; int bt = 2;
#pragma unroll
      for (int t = 0; t < 2; ++t) {
        if (((cm >> t) & 1u) && v2[t] > bv) { bv = v2[t]; bj = j2[t]; bt = t; }
      }
      float rv = bv; int rj = bj;
#pragma unroll
      for (int s = 1; s < 64; s <<= 1) {
        const float ov = __shfl_xor(rv, s);
        const int   oj = __shfl_xor(rj, s);
        if (ov > rv || (ov == rv && oj < rj)) { rv = ov; rj = oj; }
      }
      if (bv == rv && bj == rj) {
        *(float2*)&cand[r][2 * (cb + it)] = make_float2(bv, __int_as_float(bj));
        cm &= ~(1u << bt);
      }
    }
    // softmax over the selected 32 (order-invariant)
    {
      const float x = cand[r][2 * (lane & 31)];
      float mx = x;
#pragma unroll
      for (int s = 16; s >= 1; s >>= 1) mx = fmaxf(mx, __shfl_xor(mx, s));
      const float e = expf(x - mx);
      float sum = e;
#pragma unroll
      for (int s = 16; s >= 1; s >>= 1) sum += __shfl_xor(sum, s);
      if (lane < KSEL) cand[r][2 * lane] = e / sum;
    }
  }
  __syncthreads();

  // write (attn, id) pairs: 512 pairs = 256 float4, one per thread
  {
    const int pidx = tid * 2;
    const int r = pidx >> 5, k = pidx & 31;
    const float4 o4 = *(const float4*)&cand[r][2 * k];
    *(float4*)&pairs[((size_t)batch * NPTS + i0 + r) * KSEL + k] = o4;
  }
}

// ====== Kernel B: transposed-LDS float4 gather (round-20 proven, frozen) ====
__global__ __launch_bounds__(256, 2) void gnn_gather(const float* __restrict__ in,
                                                     const float2* __restrict__ pairs,
                                                     float* __restrict__ out) {
  __shared__ float fst[4][4096];       // per-wave 16 KB: 1024 granules x 16B

  const int p     = blockIdx.x;
  const int batch = ((p & 7) << 1) | ((p >> 3) & 1);
  const int chunk = p >> 4;            // 0..31
  const int i0    = chunk * 32;
  const int tid   = threadIdx.x;
  const int w     = tid >> 6;
  const int lane  = tid & 63;
  const int row   = lane & 31;
  const int khalf = lane >> 5;
  const int ch0   = w * 64;

  const float* __restrict__ fbase = in + (size_t)batch * CT * NPTS;
  float* const fw = &fst[w][0];

  float a16[16]; int jjb[16];
  {
    const float4* pr4 = (const float4*)(pairs + ((size_t)batch * NPTS + i0 + row) * KSEL)
                        + khalf * 8;
#pragma unroll
    for (int qq = 0; qq < 8; ++qq) {
      const float4 o = pr4[qq];
      const int id0 = __float_as_int(o.y);
      const int id1 = __float_as_int(o.w);
      a16[2*qq]   = o.x;
      jjb[2*qq]   = ((((id0 & 3) << 6) | ((id0 >> 2) & 63) | (id0 & ~255)) << 4);
      a16[2*qq+1] = o.z;
      jjb[2*qq+1] = ((((id1 & 3) << 6) | ((id1 >> 2) & 63) | (id1 & ~255)) << 4);
    }
  }

  float4 tile[4][4];

#define LOADT(pp)                                                                \
  do {                                                                           \
    _Pragma("unroll")                                                            \
    for (int it = 0; it < 4; ++it) {                                             \
      _Pragma("unroll")                                                          \
      for (int c = 0; c < 4; ++c)                                                \
        tile[it][c] = *(const float4*)(fbase +                                   \
            (size_t)(ch0 + (pp) * 4 + c) * NPTS + it * 256 + lane * 4);          \
    }                                                                            \
  } while (0)

#define WRITET()                                                                 \
  do {                                                                           \
    _Pragma("unroll")                                                            \
    for (int it = 0; it < 4; ++it) {                                             \
      *(float4*)&fw[(256*it + lane) * 4] =                                       \
          make_float4(tile[it][0].x, tile[it][1].x, tile[it][2].x, tile[it][3].x);\
      *(float4*)&fw[(256*it + 64 + lane) * 4] =                                  \
          make_float4(tile[it][0].y, tile[it][1].y, tile[it][2].y, tile[it][3].y);\
      *(float4*)&fw[(256*it + 128 + lane) * 4] =                                 \
          make_float4(tile[it][0].z, tile[it][1].z, tile[it][2].z, tile[it][3].z);\
      *(float4*)&fw[(256*it + 192 + lane) * 4] =                                 \
          make_float4(tile[it][0].w, tile[it][1].w, tile[it][2].w, tile[it][3].w);\
    }                                                                            \
  } while (0)

  LOADT(0);
  WRITET();

  for (int pp = 0; pp < 16; ++pp) {
    if (pp < 15) LOADT(pp + 1);

    float4 o4 = make_float4(0.f, 0.f, 0.f, 0.f);
#pragma unroll
    for (int kk = 0; kk < 16; ++kk) {
      const float4 f4 = *(const float4*)((const char*)fw + jjb[kk]);
      const float ak = a16[kk];
      o4.x = fmaf(ak, f4.x, o4.x);
      o4.y = fmaf(ak, f4.y, o4.y);
      o4.z = fmaf(ak, f4.z, o4.z);
      o4.w = fmaf(ak, f4.w, o4.w);
    }
    o4.x += __shfl_xor(o4.x, 32);
    o4.y += __shfl_xor(o4.y, 32);
    o4.z += __shfl_xor(o4.z, 32);
    o4.w += __shfl_xor(o4.w, 32);

    float* ob = out + ((size_t)batch * DFEAT + ch0 + pp * 4) * NPTS + i0 + row;
    if (khalf == 0) {
      ob[0]            = o4.x;
      ob[(size_t)NPTS] = o4.y;
    } else {
      ob[(size_t)2 * NPTS] = o4.z;
      ob[(size_t)3 * NPTS] = o4.w;
    }

    if (pp < 15) WRITET();
  }
#undef LOADT
#undef WRITET
}

extern "C" void kernel_launch(void* const* d_in, const int* in_sizes, int n_in,
                              void* d_out, int out_size, void* d_ws, size_t ws_size,
                              hipStream_t stream) {
  const float* in = (const float*)d_in[0];
  float* out = (float*)d_out;
  float2* pairs = (float2*)d_ws;                                    // 4 MB
  unsigned short* ph0 = (unsigned short*)((char*)d_ws + (4u << 20)); // 2 MB
  unsigned short* ph1 = (unsigned short*)((char*)d_ws + (6u << 20)); // 2 MB
  unsigned short* ph2 = (unsigned short*)((char*)d_ws + (8u << 20)); // 2 MB
  gnn_phat<<<dim3(64), dim3(256), 0, stream>>>(in, ph0, ph1, ph2);
  gnn_sim_topk<<<dim3(1024), dim3(256), 0, stream>>>(ph0, ph1, ph2, pairs);
  gnn_gather<<<dim3(512), dim3(256), 0, stream>>>(in, pairs, out);
}